// Round 1
// baseline (2842.348 us; speedup 1.0000x reference)
//
#include <hip/hip_runtime.h>
#include <math.h>

#define NPB 4  // particles (waves) per block

// ---------------- prep: pack Kopen rows (64x16, 64B-aligned) + symA + sumA2 into ws
__global__ void otflow_prep(const float* __restrict__ K0g,
                            const float* __restrict__ Ag,
                            float* __restrict__ ws) {
  __shared__ float Als[170];
  int tid = threadIdx.x;
  for (int idx = tid; idx < 1024; idx += 256) {
    int m = idx >> 4, d = idx & 15;
    ws[idx] = K0g[m * 17 + d];
  }
  if (tid < 170) Als[tid] = Ag[tid];
  __syncthreads();
  for (int idx = tid; idx < 289; idx += 256) {
    int j = idx / 17, k = idx % 17;
    float s = 0.f;
#pragma unroll
    for (int r = 0; r < 10; ++r) s += Als[r * 17 + j] * Als[r * 17 + k];
    ws[1024 + idx] = s;
  }
  __syncthreads();
  if (tid == 0) {
    float s = 0.f;
    for (int r = 0; r < 10; ++r)
      for (int j = 0; j < 16; ++j) { float v = Als[r * 17 + j]; s += v * v; }
    ws[1313] = s;
  }
}

// ---------------- main: one wave integrates one particle through all nt RK4 steps
__global__ __launch_bounds__(256) void otflow_main(
    const float* __restrict__ xg, const float* __restrict__ wg,
    const float* __restrict__ bg, const float* __restrict__ K0g,
    const float* __restrict__ b0g, const float* __restrict__ K1g,
    const float* __restrict__ b1g, const int* __restrict__ ntg,
    const float* __restrict__ ws, float* __restrict__ out, int n) {
  __shared__ float K1T[64 * 65];   // K1T[m*65+i] = K1[i][m]; stride 65 -> conflict-free both ways
  __shared__ float K0s[64 * 17];   // row-major K0
  __shared__ float symA[304];      // 17x17
  __shared__ float scr[NPB][288];  // per-wave: u0[64] c[64] a[64] r[64] g[17..]

  const int tid = threadIdx.x;
  const int lane = tid & 63;
  const int wid = tid >> 6;

  for (int idx = tid; idx < 64 * 64; idx += 256) {
    int i = idx >> 6, m = idx & 63;
    K1T[m * 65 + i] = K1g[idx];
  }
  for (int idx = tid; idx < 64 * 17; idx += 256) K0s[idx] = K0g[idx];
  for (int idx = tid; idx < 289; idx += 256) symA[idx] = ws[1024 + idx];
  __syncthreads();

  const float b0_r = b0g[lane];
  const float w_r = wg[lane];
  const float b1_r = b1g[lane];
  const float b_r = (lane < 17) ? bg[lane] : 0.0f;
  const float sumA2 = ws[1313];
  float k0sq = 0.f;
#pragma unroll
  for (int d = 0; d < 16; ++d) { float v = K0s[lane * 17 + d]; k0sq += v * v; }

  const int nt = *ntg;
  const float h = 1.0f / (float)nt;

  int p = blockIdx.x * NPB + wid;
  if (p >= n) p = n - 1;  // benign duplicate (grid is exact for n=32768)

  float* u0s = scr[wid];
  float* cs = scr[wid] + 64;
  float* avs = scr[wid] + 128;
  float* rvs = scr[wid] + 192;
  float* gvs = scr[wid] + 256;

  float x0[16], xin[16], xacc[16];
  {
    const float* xp = xg + (size_t)p * 16;
#pragma unroll
    for (int j = 0; j < 16; ++j) { float v = xp[j]; x0[j] = v; xin[j] = v; xacc[j] = v; }
  }
  float lacc = 0.f, vacc = 0.f, racc = 0.f;

  for (int k = 0; k < nt; ++k) {
    float t0 = (float)k * h;
#pragma unroll 1
    for (int st = 0; st < 4; ++st) {
      float tin = t0 + ((st == 0) ? 0.f : (st == 3) ? h : 0.5f * h);

      // ---- opening (lane = m): o = b0[m] + K0[m,:]·s
      float o = b0_r + K0s[lane * 17 + 16] * tin;
#pragma unroll
      for (int j = 0; j < 16; ++j) o += K0s[lane * 17 + j] * xin[j];

      float ao = fabsf(o);
      float u0 = ao + __logf(1.0f + __expf(-2.0f * ao));
      float Eo = __expf(2.0f * o);
      float c = 1.0f - 2.0f / (Eo + 1.0f);  // tanh(o)
      float dt0 = 1.0f - c * c;
      u0s[lane] = u0;
      cs[lane] = c;
      __syncthreads();

      // ---- feat1 (lane = i): f = b1[i] + K1[i,:]·u0
      float f = b1_r;
#pragma unroll 4
      for (int mm = 0; mm < 64; mm += 4) {
        float4 u4 = *(const float4*)(u0s + mm);
        f += K1T[(mm + 0) * 65 + lane] * u4.x;
        f += K1T[(mm + 1) * 65 + lane] * u4.y;
        f += K1T[(mm + 2) * 65 + lane] * u4.z;
        f += K1T[(mm + 3) * 65 + lane] * u4.w;
      }
      float Ef = __expf(2.0f * f);
      float tf = 1.0f - 2.0f / (Ef + 1.0f);  // tanh(f)
      float q = (1.0f - tf * tf) * w_r;      // dtanh(feat1)*w
      avs[lane] = tf * w_r;
      __syncthreads();

      // ---- z1 (lane = m): z1[m] = w[m] + sum_i a[i]*K1[i][m]
      float z1 = 0.f;
#pragma unroll 4
      for (int ii = 0; ii < 64; ii += 4) {
        float4 a4 = *(const float4*)(avs + ii);
        z1 += K1T[lane * 65 + ii + 0] * a4.x;
        z1 += K1T[lane * 65 + ii + 1] * a4.y;
        z1 += K1T[lane * 65 + ii + 2] * a4.z;
        z1 += K1T[lane * 65 + ii + 3] * a4.w;
      }
      z1 += w_r;
      float rv = c * z1;
      float trh_p = dt0 * z1 * k0sq;
      rvs[lane] = rv;
      __syncthreads();

      // ---- KJ (lane = i): kj[d] = sum_m K1[i][m]*c[m]*Kopen[m][d]; Kopen rows via uniform
      //      (scalarizable) loads from packed ws -> stays off the LDS pipe.
      float kj[16];
#pragma unroll
      for (int d = 0; d < 16; ++d) kj[d] = 0.f;
#pragma unroll 2
      for (int mm = 0; mm < 64; mm += 4) {
        float4 c4 = *(const float4*)(cs + mm);
#pragma unroll
        for (int u = 0; u < 4; ++u) {
          float cu = (u == 0) ? c4.x : (u == 1) ? c4.y : (u == 2) ? c4.z : c4.w;
          int m = mm + u;
          float a = K1T[m * 65 + lane] * cu;
          const float4* kp = (const float4*)(ws + (m << 4));
          float4 A0 = kp[0], A1 = kp[1], A2 = kp[2], A3 = kp[3];
          kj[0] += a * A0.x;  kj[1] += a * A0.y;  kj[2] += a * A0.z;  kj[3] += a * A0.w;
          kj[4] += a * A1.x;  kj[5] += a * A1.y;  kj[6] += a * A1.z;  kj[7] += a * A1.w;
          kj[8] += a * A2.x;  kj[9] += a * A2.y;  kj[10] += a * A2.z; kj[11] += a * A2.w;
          kj[12] += a * A3.x; kj[13] += a * A3.y; kj[14] += a * A3.z; kj[15] += a * A3.w;
        }
      }
      float ssq = 0.f;
#pragma unroll
      for (int d = 0; d < 16; ++d) ssq += kj[d] * kj[d];
      float t1v = q * ssq;
      float trhv = trh_p;
#pragma unroll
      for (int off = 1; off < 64; off <<= 1) {
        trhv += __shfl_xor(trhv, off, 64);
        t1v += __shfl_xor(t1v, off, 64);
      }
      float trH = trhv + t1v + sumA2;

      // ---- grad (lane = j < 17): g[j] = b[j] + sum_m r[m]*K0[m][j] + s·symA[:,j]
      if (lane < 17) {
        float g = b_r;
#pragma unroll 4
        for (int mm = 0; mm < 64; mm += 4) {
          float4 r4 = *(const float4*)(rvs + mm);
          g += r4.x * K0s[(mm + 0) * 17 + lane];
          g += r4.y * K0s[(mm + 1) * 17 + lane];
          g += r4.z * K0s[(mm + 2) * 17 + lane];
          g += r4.w * K0s[(mm + 3) * 17 + lane];
        }
#pragma unroll
        for (int k2 = 0; k2 < 16; ++k2) g += xin[k2] * symA[k2 * 17 + lane];
        g += tin * symA[16 * 17 + lane];
        gvs[lane] = g;
      }
      __syncthreads();

      // ---- replicated RK4 update (all lanes identical)
      float dv = 0.f;
      float kx[16];
#pragma unroll
      for (int j = 0; j < 16; ++j) { float dx = -gvs[j]; kx[j] = dx; dv += dx * dx; }
      dv *= 0.5f;
      float dl = -trH;
      float dr = fabsf(dv - gvs[16]);  // |-gradPhi[-1] + ALPHA0*dv|, ALPHA0=1
      float wc = (st == 0 || st == 3) ? (1.0f / 6.0f) : (1.0f / 3.0f);
#pragma unroll
      for (int j = 0; j < 16; ++j) xacc[j] += wc * h * kx[j];
      lacc += wc * h * dl;
      vacc += wc * h * dv;
      racc += wc * h * dr;
      if (st < 3) {
        float an = (st == 2) ? 1.0f : 0.5f;
#pragma unroll
        for (int j = 0; j < 16; ++j) xin[j] = x0[j] + an * h * kx[j];
      } else {
#pragma unroll
        for (int j = 0; j < 16; ++j) { x0[j] = xacc[j]; xin[j] = xacc[j]; }
      }
    }
  }

  // ---- outputs: x (n,16) then l, v, r
  size_t base = (size_t)p * 16;
#pragma unroll
  for (int j = 0; j < 16; ++j)
    if (lane == j) out[base + j] = xacc[j];
  if (lane == 16) out[(size_t)n * 16 + p] = lacc;
  if (lane == 17) out[(size_t)n * 16 + n + p] = vacc;
  if (lane == 18) out[(size_t)n * 16 + 2 * (size_t)n + p] = racc;
}

extern "C" void kernel_launch(void* const* d_in, const int* in_sizes, int n_in,
                              void* d_out, int out_size, void* d_ws, size_t ws_size,
                              hipStream_t stream) {
  const float* xg = (const float*)d_in[0];
  const float* wg = (const float*)d_in[1];
  const float* Ag = (const float*)d_in[2];
  const float* bg = (const float*)d_in[3];
  const float* K0g = (const float*)d_in[4];
  const float* b0g = (const float*)d_in[5];
  const float* K1g = (const float*)d_in[6];
  const float* b1g = (const float*)d_in[7];
  const int* ntg = (const int*)d_in[8];
  float* out = (float*)d_out;
  float* ws = (float*)d_ws;
  int n = in_sizes[0] / 16;

  hipLaunchKernelGGL(otflow_prep, dim3(1), dim3(256), 0, stream, K0g, Ag, ws);
  int nblocks = (n + NPB - 1) / NPB;
  hipLaunchKernelGGL(otflow_main, dim3(nblocks), dim3(256), 0, stream,
                     xg, wg, bg, K0g, b0g, K1g, b1g, ntg, ws, out, n);
}

// Round 2
// 958.283 us; speedup vs baseline: 2.9661x; 2.9661x over previous
//
#include <hip/hip_runtime.h>
#include <math.h>

typedef __attribute__((ext_vector_type(8))) short bf16x8;
typedef __attribute__((ext_vector_type(4))) float f32x4;

union B8 { bf16x8 v; unsigned u[4]; };

__device__ __forceinline__ unsigned pk2(float lo, float hi) {
  unsigned r;
  asm("v_cvt_pk_bf16_f32 %0, %1, %2" : "=v"(r) : "v"(lo), "v"(hi));
  return r;
}
__device__ __forceinline__ float rcpf(float x) { return __builtin_amdgcn_rcpf(x); }

#define MFMA __builtin_amdgcn_mfma_f32_16x16x32_bf16

// ---------------- prep: pack Kopen rows (64x16) + symA (17x17) + sumA2 into ws
__global__ void otflow_prep(const float* __restrict__ K0g,
                            const float* __restrict__ Ag,
                            float* __restrict__ ws) {
  __shared__ float Als[170];
  int tid = threadIdx.x;
  for (int idx = tid; idx < 1024; idx += 256) {
    int m = idx >> 4, d = idx & 15;
    ws[idx] = K0g[m * 17 + d];
  }
  if (tid < 170) Als[tid] = Ag[tid];
  __syncthreads();
  for (int idx = tid; idx < 289; idx += 256) {
    int j = idx / 17, k = idx % 17;
    float s = 0.f;
#pragma unroll
    for (int r = 0; r < 10; ++r) s += Als[r * 17 + j] * Als[r * 17 + k];
    ws[1024 + idx] = s;
  }
  __syncthreads();
  if (tid == 0) {
    float s = 0.f;
    for (int r = 0; r < 10; ++r)
      for (int j = 0; j < 16; ++j) { float v = Als[r * 17 + j]; s += v * v; }
    ws[1313] = s;
  }
}

// build two K-block B8 frags (bf16) from 8+8 consecutive f32 in LDS at base[off], base[32+off]
__device__ __forceinline__ void bld2(const float* base, int off, B8& lo, B8& hi) {
  float4 a0 = *(const float4*)(base + off);
  float4 a1 = *(const float4*)(base + off + 4);
  float4 a2 = *(const float4*)(base + 32 + off);
  float4 a3 = *(const float4*)(base + 32 + off + 4);
  lo.u[0] = pk2(a0.x, a0.y); lo.u[1] = pk2(a0.z, a0.w);
  lo.u[2] = pk2(a1.x, a1.y); lo.u[3] = pk2(a1.z, a1.w);
  hi.u[0] = pk2(a2.x, a2.y); hi.u[1] = pk2(a2.z, a2.w);
  hi.u[2] = pk2(a3.x, a3.y); hi.u[3] = pk2(a3.z, a3.w);
}

// ---------------- main: one wave (= one workgroup) per particle, all nt RK4 steps
__global__ __launch_bounds__(64, 2) void otflow_main(
    const float* __restrict__ xg, const float* __restrict__ wg,
    const float* __restrict__ bg, const float* __restrict__ K0g,
    const float* __restrict__ b0g, const float* __restrict__ K1g,
    const float* __restrict__ b1g, const int* __restrict__ ntg,
    const float* __restrict__ ws, float* __restrict__ out, int n) {
  __shared__ float K0s[1088];                 // K0 row-major 64x17
  __shared__ float u0s[64], cs[64], avs[64], qs[64], rvs[64], fs[64], gvs[20];

  const int lane = threadIdx.x;
  const int lg = lane >> 4;     // lane group (k-slot group)
  const int lr = lane & 15;     // row/col within 16

  for (int idx = lane; idx < 1088; idx += 64) K0s[idx] = K0g[idx];
  __syncthreads();

  const float b0_r = b0g[lane];
  const float w_r  = wg[lane];
  const float b1_r = b1g[lane];
  const float sumA2 = ws[1313];
  float k0sq = 0.f;
#pragma unroll
  for (int d = 0; d < 16; ++d) { float v = K0s[lane * 17 + d]; k0sq += v * v; }

  // ---- const fragment preloads (bf16) ----
  // A = K1: row i = mi*16+lr, k m = kb*32+lg*8+j   (used by feat1, KJ)
  B8 aK1[8];
#pragma unroll
  for (int mi = 0; mi < 4; ++mi)
#pragma unroll
    for (int kb = 0; kb < 2; ++kb) {
      const float* pp = K1g + (mi * 16 + lr) * 64 + kb * 32 + lg * 8;
      float4 q0 = *(const float4*)pp;
      float4 q1 = *(const float4*)(pp + 4);
      B8 t;
      t.u[0] = pk2(q0.x, q0.y); t.u[1] = pk2(q0.z, q0.w);
      t.u[2] = pk2(q1.x, q1.y); t.u[3] = pk2(q1.z, q1.w);
      aK1[mi * 2 + kb] = t;
    }
  // B = K1: col m = nb*16+lr, k i = kb*32+lg*8+j   (used by z1, broadcast-A)
  B8 bK1[8];
#pragma unroll
  for (int nb = 0; nb < 4; ++nb)
#pragma unroll
    for (int kb = 0; kb < 2; ++kb) {
      int m = nb * 16 + lr;
      int ib = kb * 32 + lg * 8;
      float e0 = K1g[(ib + 0) * 64 + m], e1 = K1g[(ib + 1) * 64 + m];
      float e2 = K1g[(ib + 2) * 64 + m], e3 = K1g[(ib + 3) * 64 + m];
      float e4 = K1g[(ib + 4) * 64 + m], e5 = K1g[(ib + 5) * 64 + m];
      float e6 = K1g[(ib + 6) * 64 + m], e7 = K1g[(ib + 7) * 64 + m];
      B8 t;
      t.u[0] = pk2(e0, e1); t.u[1] = pk2(e2, e3);
      t.u[2] = pk2(e4, e5); t.u[3] = pk2(e6, e7);
      bK1[nb * 2 + kb] = t;
    }
  // B = [K0 | symA | b]: col j = min(nb*16+lr,16), k = kb*32+lg*8+jj (K=96) (grad)
  B8 bG[6];
#pragma unroll
  for (int nb = 0; nb < 2; ++nb)
#pragma unroll
    for (int kb = 0; kb < 3; ++kb) {
      int j = nb * 16 + lr; if (j > 16) j = 16;
      float e[8];
#pragma unroll
      for (int jj = 0; jj < 8; ++jj) {
        float v;
        if (kb < 2) {
          int k = kb * 32 + lg * 8 + jj;        // 0..63 -> K0[k][j]
          v = K0g[k * 17 + j];
        } else {
          int kr = lg * 8 + jj;                 // 0..31
          v = (kr < 17) ? ws[1024 + kr * 17 + j] : (kr == 17) ? bg[j] : 0.f;
        }
        e[jj] = v;
      }
      B8 t;
      t.u[0] = pk2(e[0], e[1]); t.u[1] = pk2(e[2], e[3]);
      t.u[2] = pk2(e[4], e[5]); t.u[3] = pk2(e[6], e[7]);
      bG[nb * 3 + kb] = t;
    }
  // Kopen[m][d] at m = kb*32+lg*8+j, d = lr  (KJ B build)
  float kop[16];
#pragma unroll
  for (int kb = 0; kb < 2; ++kb)
#pragma unroll
    for (int j = 0; j < 8; ++j)
      kop[kb * 8 + j] = ws[(kb * 32 + lg * 8 + j) * 16 + lr];

  const f32x4 zz = {0.f, 0.f, 0.f, 0.f};
  const int nt = *ntg;
  const float h = 1.0f / (float)nt;
  const int p = blockIdx.x;

  float x0[16], xin[16], xacc[16];
  {
    const float* xp = xg + (size_t)p * 16;
#pragma unroll
    for (int j = 0; j < 16; ++j) { float v = xp[j]; x0[j] = v; xin[j] = v; xacc[j] = v; }
  }
  float lacc = 0.f, vacc = 0.f, racc = 0.f;

  for (int k = 0; k < nt; ++k) {
    float t0 = (float)k * h;
#pragma unroll 1
    for (int st = 0; st < 4; ++st) {
      float tin = t0 + ((st == 0) ? 0.f : (st == 3) ? h : 0.5f * h);

      // ---- phase 1: opening (lane = m), fp32
      float o = b0_r + K0s[lane * 17 + 16] * tin;
#pragma unroll
      for (int j = 0; j < 16; ++j) o += K0s[lane * 17 + j] * xin[j];
      float Eo = __expf(2.f * o);
      float c = 1.f - 2.f * rcpf(Eo + 1.f);          // tanh(o)
      float eabs = (o >= 0.f) ? rcpf(Eo) : Eo;       // e^{-2|o|}
      float u0 = fabsf(o) + __logf(1.f + eabs);
      float dt0 = 1.f - c * c;
      u0s[lane] = u0; cs[lane] = c;
      __syncthreads();  // F1

      // ---- phase 2: feat1 = K1 @ u0 (A=K1 frags, B=u0 broadcast-cols)
      {
        B8 uf0, uf1; bld2(u0s, lg * 8, uf0, uf1);
#pragma unroll
        for (int mi = 0; mi < 4; ++mi) {
          f32x4 fa = MFMA(aK1[mi * 2].v, uf0.v, zz, 0, 0, 0);
          fa = MFMA(aK1[mi * 2 + 1].v, uf1.v, fa, 0, 0, 0);
          if (lr == 0) *(f32x4*)(fs + mi * 16 + lg * 4) = fa;
        }
      }
      __syncthreads();  // F2
      float fv = fs[lane] + b1_r;

      // ---- phase 3: elementwise (lane = i)
      float Ef = __expf(2.f * fv);
      float tf = 1.f - 2.f * rcpf(Ef + 1.f);
      float q = (1.f - tf * tf) * w_r;
      float a = tf * w_r;
      avs[lane] = a; qs[lane] = q;
      __syncthreads();  // F3

      // ---- phase 4: z1 = a @ K1 (broadcast-A rows, B=K1 frags) — no redistribution
      float z1;
      {
        B8 af0, af1; bld2(avs, lg * 8, af0, af1);
        f32x4 z0v = MFMA(af0.v, bK1[0].v, zz, 0, 0, 0); z0v = MFMA(af1.v, bK1[1].v, z0v, 0, 0, 0);
        f32x4 z1v = MFMA(af0.v, bK1[2].v, zz, 0, 0, 0); z1v = MFMA(af1.v, bK1[3].v, z1v, 0, 0, 0);
        f32x4 z2v = MFMA(af0.v, bK1[4].v, zz, 0, 0, 0); z2v = MFMA(af1.v, bK1[5].v, z2v, 0, 0, 0);
        f32x4 z3v = MFMA(af0.v, bK1[6].v, zz, 0, 0, 0); z3v = MFMA(af1.v, bK1[7].v, z3v, 0, 0, 0);
        float zlo = (lg & 1) ? z1v[0] : z0v[0];
        float zhi = (lg & 1) ? z3v[0] : z2v[0];
        z1 = ((lg & 2) ? zhi : zlo) + w_r;             // z1[lane]
      }
      float rv = c * z1;
      float trh = dt0 * z1 * k0sq;
      rvs[lane] = rv;

      // ---- phase 5: KJ = K1 @ (c (.) Kopen), t1 folded via C/D layout
      float part = 0.f;
      {
        B8 y0, y1;
        float4 c0 = *(const float4*)(cs + lg * 8);
        float4 c1 = *(const float4*)(cs + lg * 8 + 4);
        float4 c2 = *(const float4*)(cs + 32 + lg * 8);
        float4 c3 = *(const float4*)(cs + 32 + lg * 8 + 4);
        y0.u[0] = pk2(c0.x * kop[0],  c0.y * kop[1]);
        y0.u[1] = pk2(c0.z * kop[2],  c0.w * kop[3]);
        y0.u[2] = pk2(c1.x * kop[4],  c1.y * kop[5]);
        y0.u[3] = pk2(c1.z * kop[6],  c1.w * kop[7]);
        y1.u[0] = pk2(c2.x * kop[8],  c2.y * kop[9]);
        y1.u[1] = pk2(c2.z * kop[10], c2.w * kop[11]);
        y1.u[2] = pk2(c3.x * kop[12], c3.y * kop[13]);
        y1.u[3] = pk2(c3.z * kop[14], c3.w * kop[15]);
#pragma unroll
        for (int mi = 0; mi < 4; ++mi) {
          f32x4 kac = MFMA(aK1[mi * 2].v, y0.v, zz, 0, 0, 0);
          kac = MFMA(aK1[mi * 2 + 1].v, y1.v, kac, 0, 0, 0);
          float4 q4 = *(const float4*)(qs + mi * 16 + lg * 4);
          part += q4.x * kac[0] * kac[0];
          part += q4.y * kac[1] * kac[1];
          part += q4.z * kac[2] * kac[2];
          part += q4.w * kac[3] * kac[3];
        }
      }
      float red = trh + part;
      __syncthreads();  // F4 (covers rvs write)

      // ---- phase 6: grad = [rv; x; t; 1] @ [K0 | symA | b]  (K=96, broadcast-A)
      {
        B8 r0, r1; bld2(rvs, lg * 8, r0, r1);
        B8 sf;
        float s0 = (lg == 0) ? xin[0] : (lg == 1) ? xin[8]  : (lg == 2) ? tin  : 0.f;
        float s1 = (lg == 0) ? xin[1] : (lg == 1) ? xin[9]  : (lg == 2) ? 1.0f : 0.f;
        float s2 = (lg == 0) ? xin[2] : (lg == 1) ? xin[10] : 0.f;
        float s3 = (lg == 0) ? xin[3] : (lg == 1) ? xin[11] : 0.f;
        float s4 = (lg == 0) ? xin[4] : (lg == 1) ? xin[12] : 0.f;
        float s5 = (lg == 0) ? xin[5] : (lg == 1) ? xin[13] : 0.f;
        float s6 = (lg == 0) ? xin[6] : (lg == 1) ? xin[14] : 0.f;
        float s7 = (lg == 0) ? xin[7] : (lg == 1) ? xin[15] : 0.f;
        sf.u[0] = pk2(s0, s1); sf.u[1] = pk2(s2, s3);
        sf.u[2] = pk2(s4, s5); sf.u[3] = pk2(s6, s7);
        f32x4 g0a = MFMA(r0.v, bG[0].v, zz, 0, 0, 0);
        g0a = MFMA(r1.v, bG[1].v, g0a, 0, 0, 0);
        g0a = MFMA(sf.v, bG[2].v, g0a, 0, 0, 0);
        f32x4 g1a = MFMA(r0.v, bG[3].v, zz, 0, 0, 0);
        g1a = MFMA(r1.v, bG[4].v, g1a, 0, 0, 0);
        g1a = MFMA(sf.v, bG[5].v, g1a, 0, 0, 0);
        if (lane < 16) gvs[lane] = g0a[0];
        if (lane == 0) gvs[16] = g1a[0];
      }
      // wave reduction of trH partial (overlaps with grad stores)
#pragma unroll
      for (int off = 1; off < 64; off <<= 1) red += __shfl_xor(red, off, 64);
      float trH = red + sumA2;
      __syncthreads();  // F5

      // ---- phase 7: RK4 update (replicated)
      float dv = 0.f;
      float kx[16];
#pragma unroll
      for (int j = 0; j < 16; ++j) { float dx = -gvs[j]; kx[j] = dx; dv += dx * dx; }
      dv *= 0.5f;
      float g16 = gvs[16];
      float dl = -trH;
      float dr = fabsf(dv - g16);
      float wc = (st == 0 || st == 3) ? (1.0f / 6.0f) : (1.0f / 3.0f);
#pragma unroll
      for (int j = 0; j < 16; ++j) xacc[j] += wc * h * kx[j];
      lacc += wc * h * dl;
      vacc += wc * h * dv;
      racc += wc * h * dr;
      if (st < 3) {
        float an = (st == 2) ? 1.0f : 0.5f;
#pragma unroll
        for (int j = 0; j < 16; ++j) xin[j] = x0[j] + an * h * kx[j];
      } else {
#pragma unroll
        for (int j = 0; j < 16; ++j) { x0[j] = xacc[j]; xin[j] = xacc[j]; }
      }
    }
  }

  // ---- outputs: x (n,16) then l, v, r
  size_t base = (size_t)p * 16;
#pragma unroll
  for (int j = 0; j < 16; ++j)
    if (lane == j) out[base + j] = xacc[j];
  if (lane == 16) out[(size_t)n * 16 + p] = lacc;
  if (lane == 17) out[(size_t)n * 16 + n + p] = vacc;
  if (lane == 18) out[(size_t)n * 16 + 2 * (size_t)n + p] = racc;
}

extern "C" void kernel_launch(void* const* d_in, const int* in_sizes, int n_in,
                              void* d_out, int out_size, void* d_ws, size_t ws_size,
                              hipStream_t stream) {
  const float* xg = (const float*)d_in[0];
  const float* wg = (const float*)d_in[1];
  const float* Ag = (const float*)d_in[2];
  const float* bg = (const float*)d_in[3];
  const float* K0g = (const float*)d_in[4];
  const float* b0g = (const float*)d_in[5];
  const float* K1g = (const float*)d_in[6];
  const float* b1g = (const float*)d_in[7];
  const int* ntg = (const int*)d_in[8];
  float* out = (float*)d_out;
  float* ws = (float*)d_ws;
  int n = in_sizes[0] / 16;

  hipLaunchKernelGGL(otflow_prep, dim3(1), dim3(256), 0, stream, K0g, Ag, ws);
  hipLaunchKernelGGL(otflow_main, dim3(n), dim3(64), 0, stream,
                     xg, wg, bg, K0g, b0g, K1g, b1g, ntg, ws, out, n);
}

// Round 3
// 358.269 us; speedup vs baseline: 7.9336x; 2.6748x over previous
//
#include <hip/hip_runtime.h>
#include <math.h>

typedef __attribute__((ext_vector_type(8))) short bf16x8;
typedef __attribute__((ext_vector_type(4))) float f32x4;

union B8 { bf16x8 v; unsigned u[4]; };

__device__ __forceinline__ unsigned pk2(float lo, float hi) {
  unsigned r;
  asm("v_cvt_pk_bf16_f32 %0, %1, %2" : "=v"(r) : "v"(lo), "v"(hi));
  return r;
}
__device__ __forceinline__ float rcpf(float x) { return __builtin_amdgcn_rcpf(x); }
__device__ __forceinline__ void ldsfence() { asm volatile("s_waitcnt lgkmcnt(0)" ::: "memory"); }

#define MFMA __builtin_amdgcn_mfma_f32_16x16x32_bf16

// ---------------- prep: Kopen pack [0..1023], symA [1024..1312], sumA2 [1313], k0sq [1320..1383]
__global__ void otflow_prep(const float* __restrict__ K0g,
                            const float* __restrict__ Ag,
                            float* __restrict__ ws) {
  __shared__ float Als[170];
  int tid = threadIdx.x;
  for (int idx = tid; idx < 1024; idx += 256) {
    int m = idx >> 4, d = idx & 15;
    ws[idx] = K0g[m * 17 + d];
  }
  if (tid < 170) Als[tid] = Ag[tid];
  if (tid < 64) {
    float s = 0.f;
    for (int d = 0; d < 16; ++d) { float v = K0g[tid * 17 + d]; s += v * v; }
    ws[1320 + tid] = s;
  }
  __syncthreads();
  for (int idx = tid; idx < 289; idx += 256) {
    int j = idx / 17, k2 = idx % 17;
    float s = 0.f;
#pragma unroll
    for (int r = 0; r < 10; ++r) s += Als[r * 17 + j] * Als[r * 17 + k2];
    ws[1024 + idx] = s;
  }
  __syncthreads();
  if (tid == 0) {
    float s = 0.f;
    for (int r = 0; r < 10; ++r)
      for (int j = 0; j < 16; ++j) { float v = Als[r * 17 + j]; s += v * v; }
    ws[1313] = s;
  }
}

// ---------------- main: one wave = 16 particles, batched in the MFMA N dim
__global__ __launch_bounds__(64, 2) void otflow_main(
    const float* __restrict__ xg, const float* __restrict__ wg,
    const float* __restrict__ bg, const float* __restrict__ K0g,
    const float* __restrict__ b0g, const float* __restrict__ K1g,
    const float* __restrict__ b1g, const int* __restrict__ ntg,
    const float* __restrict__ ws, float* __restrict__ out, int n) {
  __shared__ float buf[16 * 68];   // bounce: [p][k], stride 68
  __shared__ float csh[16 * 68];   // c rows for KJ
  __shared__ float qsh[16 * 68];   // q rows for KJ
  __shared__ float tsh[16 * 20];   // per-particle t1 partials
  __shared__ float b1s[64], wss[64], k0qs[64], b0s[64], tcs[64];

  const int lane = threadIdx.x;
  const int lr = lane & 15;
  const int lg = lane >> 4;

  b1s[lane] = b1g[lane];
  wss[lane] = wg[lane];
  k0qs[lane] = ws[1320 + lane];
  b0s[lane] = b0g[lane];
  tcs[lane] = K0g[lane * 17 + 16];

  const float sumA2 = ws[1313];

  // ---- const fragments (bf16) ----
  B8 aK0[4], aK0L[4], aK1[8], aK1T[8], aG[6];
  float kop[16];
#pragma unroll
  for (int mi = 0; mi < 4; ++mi) {        // K0 hi/lo, dup over both 16-slot halves
    B8 th, tl;
#pragma unroll
    for (int jj = 0; jj < 4; ++jj) {
      float e0 = K0g[(mi * 16 + lr) * 17 + (lg & 1) * 8 + jj * 2];
      float e1 = K0g[(mi * 16 + lr) * 17 + (lg & 1) * 8 + jj * 2 + 1];
      unsigned hh = pk2(e0, e1);
      th.u[jj] = hh;
      float l0 = e0 - __uint_as_float(hh << 16);
      float l1 = e1 - __uint_as_float(hh & 0xffff0000u);
      tl.u[jj] = pk2(l0, l1);
    }
    aK0[mi] = th; aK0L[mi] = tl;
  }
#pragma unroll
  for (int mi = 0; mi < 4; ++mi)
#pragma unroll
    for (int kb = 0; kb < 2; ++kb) {
      const float* pp = K1g + (mi * 16 + lr) * 64 + kb * 32 + lg * 8;
      float4 q0 = *(const float4*)pp;
      float4 q1 = *(const float4*)(pp + 4);
      B8 t;
      t.u[0] = pk2(q0.x, q0.y); t.u[1] = pk2(q0.z, q0.w);
      t.u[2] = pk2(q1.x, q1.y); t.u[3] = pk2(q1.z, q1.w);
      aK1[mi * 2 + kb] = t;
    }
#pragma unroll
  for (int mi = 0; mi < 4; ++mi)
#pragma unroll
    for (int kb = 0; kb < 2; ++kb) {
      int ib = kb * 32 + lg * 8;
      int m = mi * 16 + lr;
      B8 t;
#pragma unroll
      for (int jj = 0; jj < 4; ++jj)
        t.u[jj] = pk2(K1g[(ib + jj * 2) * 64 + m], K1g[(ib + jj * 2 + 1) * 64 + m]);
      aK1T[mi * 2 + kb] = t;
    }
#pragma unroll
  for (int nb = 0; nb < 2; ++nb)
#pragma unroll
    for (int kb = 0; kb < 3; ++kb) {
      int j = nb * 16 + lr; if (j > 16) j = 16;
      float e[8];
#pragma unroll
      for (int jj = 0; jj < 8; ++jj) {
        float v;
        if (kb < 2) v = K0g[(kb * 32 + lg * 8 + jj) * 17 + j];
        else {
          int kr = lg * 8 + jj;
          v = (kr < 17) ? ws[1024 + kr * 17 + j] : (kr == 17) ? bg[j] : 0.f;
        }
        e[jj] = v;
      }
      B8 t;
      t.u[0] = pk2(e[0], e[1]); t.u[1] = pk2(e[2], e[3]);
      t.u[2] = pk2(e[4], e[5]); t.u[3] = pk2(e[6], e[7]);
      aG[nb * 3 + kb] = t;
    }
#pragma unroll
  for (int kb = 0; kb < 2; ++kb)
#pragma unroll
    for (int j = 0; j < 8; ++j)
      kop[kb * 8 + j] = ws[(kb * 32 + lg * 8 + j) * 16 + lr];

  ldsfence();

  const int nt = *ntg;
  const float h = 1.0f / (float)nt;
  const int p0 = blockIdx.x * 16;
  int pidx = p0 + lr; if (pidx >= n) pidx = n - 1;

  float xin[4], x0s[4], xac[4];
  {
    float4 xi = *(const float4*)(xg + (size_t)pidx * 16 + lg * 4);
    xin[0] = xi.x; xin[1] = xi.y; xin[2] = xi.z; xin[3] = xi.w;
#pragma unroll
    for (int r = 0; r < 4; ++r) { x0s[r] = xin[r]; xac[r] = xin[r]; }
  }
  float lacc = 0.f, vacc = 0.f, racc = 0.f;
  const f32x4 zz = {0.f, 0.f, 0.f, 0.f};

  for (int kstep = 0; kstep < nt; ++kstep) {
    float t0 = (float)kstep * h;
#pragma unroll 1
    for (int st = 0; st < 4; ++st) {
      float tin = t0 + ((st == 0) ? 0.f : (st == 3) ? h : 0.5f * h);

      // ---- S build: x -> buf -> hi/lo B-frag (opening) + [x;t;1] B-frag (grad)
      { float4 xv = {xin[0], xin[1], xin[2], xin[3]};
        *(float4*)(buf + lr * 68 + lg * 4) = xv; }
      ldsfence();
      float4 s0 = *(const float4*)(buf + lr * 68 + (lg & 1) * 8);
      float4 s1 = *(const float4*)(buf + lr * 68 + (lg & 1) * 8 + 4);
      unsigned h0 = pk2(s0.x, s0.y), h1 = pk2(s0.z, s0.w);
      unsigned h2 = pk2(s1.x, s1.y), h3 = pk2(s1.z, s1.w);
      B8 sfO, sfG;
      if (lg < 2) {
        sfO.u[0] = h0; sfO.u[1] = h1; sfO.u[2] = h2; sfO.u[3] = h3;
        sfG.u[0] = h0; sfG.u[1] = h1; sfG.u[2] = h2; sfG.u[3] = h3;
      } else {
        float l0 = s0.x - __uint_as_float(h0 << 16);
        float l1 = s0.y - __uint_as_float(h0 & 0xffff0000u);
        float l2 = s0.z - __uint_as_float(h1 << 16);
        float l3 = s0.w - __uint_as_float(h1 & 0xffff0000u);
        float l4 = s1.x - __uint_as_float(h2 << 16);
        float l5 = s1.y - __uint_as_float(h2 & 0xffff0000u);
        float l6 = s1.z - __uint_as_float(h3 << 16);
        float l7 = s1.w - __uint_as_float(h3 & 0xffff0000u);
        sfO.u[0] = pk2(l0, l1); sfO.u[1] = pk2(l2, l3);
        sfO.u[2] = pk2(l4, l5); sfO.u[3] = pk2(l6, l7);
        if (lg == 2) { sfG.u[0] = pk2(tin, 1.f); sfG.u[1] = 0; sfG.u[2] = 0; sfG.u[3] = 0; }
        else { sfG.u[0] = 0; sfG.u[1] = 0; sfG.u[2] = 0; sfG.u[3] = 0; }
      }

      // ---- opening: o = K0hi.x + K0lo.x (hi/lo over both operands), + b0 + t*K0[:,16]
      f32x4 o0 = MFMA(aK0[0].v, sfO.v, zz, 0, 0, 0);
      f32x4 o1 = MFMA(aK0[1].v, sfO.v, zz, 0, 0, 0);
      f32x4 o2 = MFMA(aK0[2].v, sfO.v, zz, 0, 0, 0);
      f32x4 o3 = MFMA(aK0[3].v, sfO.v, zz, 0, 0, 0);
      o0 = MFMA(aK0L[0].v, sfO.v, o0, 0, 0, 0);
      o1 = MFMA(aK0L[1].v, sfO.v, o1, 0, 0, 0);
      o2 = MFMA(aK0L[2].v, sfO.v, o2, 0, 0, 0);
      o3 = MFMA(aK0L[3].v, sfO.v, o3, 0, 0, 0);

      float cva[16];
#pragma unroll
      for (int mi = 0; mi < 4; ++mi) {
        f32x4 oa = (mi == 0) ? o0 : (mi == 1) ? o1 : (mi == 2) ? o2 : o3;
        float4 b0v = *(const float4*)(b0s + mi * 16 + lg * 4);
        float4 tcv = *(const float4*)(tcs + mi * 16 + lg * 4);
        float4 u0v;
#pragma unroll
        for (int r = 0; r < 4; ++r) {
          float ov = oa[r] + fmaf(tin, ((const float*)&tcv)[r], ((const float*)&b0v)[r]);
          float e = __expf(-2.f * fabsf(ov));
          float rp = rcpf(1.f + e);
          float cm = (1.f - e) * rp;
          cva[mi * 4 + r] = __builtin_copysignf(cm, ov);
          ((float*)&u0v)[r] = fabsf(ov) + __logf(1.f + e);
        }
        *(float4*)(buf + lr * 68 + mi * 16 + lg * 4) = u0v;
      }
      ldsfence();

      // ---- feat1 = K1 @ u0
      B8 uf0, uf1;
      {
        const float* bp = buf + lr * 68;
        float4 a0 = *(const float4*)(bp + lg * 8);
        float4 a1 = *(const float4*)(bp + lg * 8 + 4);
        float4 a2 = *(const float4*)(bp + 32 + lg * 8);
        float4 a3 = *(const float4*)(bp + 32 + lg * 8 + 4);
        uf0.u[0] = pk2(a0.x, a0.y); uf0.u[1] = pk2(a0.z, a0.w);
        uf0.u[2] = pk2(a1.x, a1.y); uf0.u[3] = pk2(a1.z, a1.w);
        uf1.u[0] = pk2(a2.x, a2.y); uf1.u[1] = pk2(a2.z, a2.w);
        uf1.u[2] = pk2(a3.x, a3.y); uf1.u[3] = pk2(a3.z, a3.w);
      }
      f32x4 f0 = MFMA(aK1[0].v, uf0.v, zz, 0, 0, 0); f0 = MFMA(aK1[1].v, uf1.v, f0, 0, 0, 0);
      f32x4 f1 = MFMA(aK1[2].v, uf0.v, zz, 0, 0, 0); f1 = MFMA(aK1[3].v, uf1.v, f1, 0, 0, 0);
      f32x4 f2 = MFMA(aK1[4].v, uf0.v, zz, 0, 0, 0); f2 = MFMA(aK1[5].v, uf1.v, f2, 0, 0, 0);
      f32x4 f3 = MFMA(aK1[6].v, uf0.v, zz, 0, 0, 0); f3 = MFMA(aK1[7].v, uf1.v, f3, 0, 0, 0);

      // ---- elementwise 2: a = tanh(f)*w, q = dtanh(f)*w
#pragma unroll
      for (int mi = 0; mi < 4; ++mi) {
        f32x4 fa = (mi == 0) ? f0 : (mi == 1) ? f1 : (mi == 2) ? f2 : f3;
        float4 b1v = *(const float4*)(b1s + mi * 16 + lg * 4);
        float4 wv = *(const float4*)(wss + mi * 16 + lg * 4);
        float4 av4, qv4;
#pragma unroll
        for (int r = 0; r < 4; ++r) {
          float fv = fa[r] + ((const float*)&b1v)[r];
          float e = __expf(-2.f * fabsf(fv));
          float rp = rcpf(1.f + e);
          float tf = __builtin_copysignf((1.f - e) * rp, fv);
          float wr = ((const float*)&wv)[r];
          ((float*)&av4)[r] = tf * wr;
          ((float*)&qv4)[r] = (1.f - tf * tf) * wr;
        }
        *(float4*)(buf + lr * 68 + mi * 16 + lg * 4) = av4;
        *(float4*)(qsh + lr * 68 + mi * 16 + lg * 4) = qv4;
      }
      ldsfence();

      // ---- z1 = K1^T @ a ; rv = c*z1 ; trh = dtanh(o)*z1*k0sq
      B8 af0, af1;
      {
        const float* bp = buf + lr * 68;
        float4 a0 = *(const float4*)(bp + lg * 8);
        float4 a1 = *(const float4*)(bp + lg * 8 + 4);
        float4 a2 = *(const float4*)(bp + 32 + lg * 8);
        float4 a3 = *(const float4*)(bp + 32 + lg * 8 + 4);
        af0.u[0] = pk2(a0.x, a0.y); af0.u[1] = pk2(a0.z, a0.w);
        af0.u[2] = pk2(a1.x, a1.y); af0.u[3] = pk2(a1.z, a1.w);
        af1.u[0] = pk2(a2.x, a2.y); af1.u[1] = pk2(a2.z, a2.w);
        af1.u[2] = pk2(a3.x, a3.y); af1.u[3] = pk2(a3.z, a3.w);
      }
      f32x4 z0 = MFMA(aK1T[0].v, af0.v, zz, 0, 0, 0); z0 = MFMA(aK1T[1].v, af1.v, z0, 0, 0, 0);
      f32x4 z1 = MFMA(aK1T[2].v, af0.v, zz, 0, 0, 0); z1 = MFMA(aK1T[3].v, af1.v, z1, 0, 0, 0);
      f32x4 z2 = MFMA(aK1T[4].v, af0.v, zz, 0, 0, 0); z2 = MFMA(aK1T[5].v, af1.v, z2, 0, 0, 0);
      f32x4 z3 = MFMA(aK1T[6].v, af0.v, zz, 0, 0, 0); z3 = MFMA(aK1T[7].v, af1.v, z3, 0, 0, 0);

      float trh_l = 0.f;
#pragma unroll
      for (int mi = 0; mi < 4; ++mi) {
        f32x4 za = (mi == 0) ? z0 : (mi == 1) ? z1 : (mi == 2) ? z2 : z3;
        float4 wv = *(const float4*)(wss + mi * 16 + lg * 4);
        float4 kq = *(const float4*)(k0qs + mi * 16 + lg * 4);
        float4 rv4, cv4;
#pragma unroll
        for (int r = 0; r < 4; ++r) {
          float c = cva[mi * 4 + r];
          float z1v = za[r] + ((const float*)&wv)[r];
          ((float*)&rv4)[r] = c * z1v;
          float dt0 = 1.f - c * c;
          trh_l = fmaf(dt0 * z1v, ((const float*)&kq)[r], trh_l);
          ((float*)&cv4)[r] = c;
        }
        *(float4*)(buf + lr * 68 + mi * 16 + lg * 4) = rv4;
        *(float4*)(csh + lr * 68 + mi * 16 + lg * 4) = cv4;
      }
      trh_l += __shfl_xor(trh_l, 16, 64);
      trh_l += __shfl_xor(trh_l, 32, 64);
      ldsfence();

      // ---- KJ per particle: kj[d][i] = sum_m (c[p,m]*Kopen[m,d]) * K1[i,m]
#pragma unroll 2
      for (int p = 0; p < 16; ++p) {
        const float* cp = csh + p * 68;
        float4 ca = *(const float4*)(cp + lg * 8);
        float4 cb = *(const float4*)(cp + lg * 8 + 4);
        float4 cc = *(const float4*)(cp + 32 + lg * 8);
        float4 cd = *(const float4*)(cp + 32 + lg * 8 + 4);
        B8 y0, y1;
        y0.u[0] = pk2(ca.x * kop[0], ca.y * kop[1]);
        y0.u[1] = pk2(ca.z * kop[2], ca.w * kop[3]);
        y0.u[2] = pk2(cb.x * kop[4], cb.y * kop[5]);
        y0.u[3] = pk2(cb.z * kop[6], cb.w * kop[7]);
        y1.u[0] = pk2(cc.x * kop[8], cc.y * kop[9]);
        y1.u[1] = pk2(cc.z * kop[10], cc.w * kop[11]);
        y1.u[2] = pk2(cd.x * kop[12], cd.y * kop[13]);
        y1.u[3] = pk2(cd.z * kop[14], cd.w * kop[15]);
        f32x4 kc0 = MFMA(y0.v, aK1[0].v, zz, 0, 0, 0); kc0 = MFMA(y1.v, aK1[1].v, kc0, 0, 0, 0);
        f32x4 kc1 = MFMA(y0.v, aK1[2].v, zz, 0, 0, 0); kc1 = MFMA(y1.v, aK1[3].v, kc1, 0, 0, 0);
        f32x4 kc2 = MFMA(y0.v, aK1[4].v, zz, 0, 0, 0); kc2 = MFMA(y1.v, aK1[5].v, kc2, 0, 0, 0);
        f32x4 kc3 = MFMA(y0.v, aK1[6].v, zz, 0, 0, 0); kc3 = MFMA(y1.v, aK1[7].v, kc3, 0, 0, 0);
        float q0 = qsh[p * 68 + lr];
        float q1 = qsh[p * 68 + 16 + lr];
        float q2 = qsh[p * 68 + 32 + lr];
        float q3 = qsh[p * 68 + 48 + lr];
        float d0 = kc0[0] * kc0[0] + kc0[1] * kc0[1] + kc0[2] * kc0[2] + kc0[3] * kc0[3];
        float d1 = kc1[0] * kc1[0] + kc1[1] * kc1[1] + kc1[2] * kc1[2] + kc1[3] * kc1[3];
        float d2 = kc2[0] * kc2[0] + kc2[1] * kc2[1] + kc2[2] * kc2[2] + kc2[3] * kc2[3];
        float d3 = kc3[0] * kc3[0] + kc3[1] * kc3[1] + kc3[2] * kc3[2] + kc3[3] * kc3[3];
        float tp = q0 * d0 + q1 * d1 + q2 * d2 + q3 * d3;
        tp += __shfl_xor(tp, 16, 64);
        tp += __shfl_xor(tp, 32, 64);
        if (lg == 0) tsh[p * 20 + lr] = tp;
      }
      ldsfence();
      float4 tv = *(const float4*)(tsh + lr * 20 + lg * 4);
      float tsum = tv.x + tv.y + tv.z + tv.w;
      tsum += __shfl_xor(tsum, 16, 64);
      tsum += __shfl_xor(tsum, 32, 64);

      // ---- grad = [rv; x; t; 1] contracted with [K0 | symA | b]
      B8 rf0, rf1;
      {
        const float* bp = buf + lr * 68;
        float4 a0 = *(const float4*)(bp + lg * 8);
        float4 a1 = *(const float4*)(bp + lg * 8 + 4);
        float4 a2 = *(const float4*)(bp + 32 + lg * 8);
        float4 a3 = *(const float4*)(bp + 32 + lg * 8 + 4);
        rf0.u[0] = pk2(a0.x, a0.y); rf0.u[1] = pk2(a0.z, a0.w);
        rf0.u[2] = pk2(a1.x, a1.y); rf0.u[3] = pk2(a1.z, a1.w);
        rf1.u[0] = pk2(a2.x, a2.y); rf1.u[1] = pk2(a2.z, a2.w);
        rf1.u[2] = pk2(a3.x, a3.y); rf1.u[3] = pk2(a3.z, a3.w);
      }
      f32x4 g0 = MFMA(aG[0].v, rf0.v, zz, 0, 0, 0);
      g0 = MFMA(aG[1].v, rf1.v, g0, 0, 0, 0);
      g0 = MFMA(aG[2].v, sfG.v, g0, 0, 0, 0);
      f32x4 g1 = MFMA(aG[3].v, rf0.v, zz, 0, 0, 0);
      g1 = MFMA(aG[4].v, rf1.v, g1, 0, 0, 0);
      g1 = MFMA(aG[5].v, sfG.v, g1, 0, 0, 0);

      // ---- RK4 update (C-layout: lane owns 4 dims of particle lr)
      float kx[4];
      float dvp = 0.f;
#pragma unroll
      for (int r = 0; r < 4; ++r) { float d = -g0[r]; kx[r] = d; dvp = fmaf(d, d, dvp); }
      dvp += __shfl_xor(dvp, 16, 64);
      dvp += __shfl_xor(dvp, 32, 64);
      dvp *= 0.5f;
      float g16 = g1[0];  // aG tile-1 rows are all j=16 -> every lane holds grad_t of its p
      float trH = trh_l + tsum + sumA2;
      float dl = -trH;
      float dr = fabsf(dvp - g16);
      float wch = ((st == 0 || st == 3) ? (1.f / 6.f) : (1.f / 3.f)) * h;
#pragma unroll
      for (int r = 0; r < 4; ++r) xac[r] = fmaf(wch, kx[r], xac[r]);
      lacc = fmaf(wch, dl, lacc);
      vacc = fmaf(wch, dvp, vacc);
      racc = fmaf(wch, dr, racc);
      if (st < 3) {
        float anh = ((st == 2) ? 1.f : 0.5f) * h;
#pragma unroll
        for (int r = 0; r < 4; ++r) xin[r] = fmaf(anh, kx[r], x0s[r]);
      } else {
#pragma unroll
        for (int r = 0; r < 4; ++r) { x0s[r] = xac[r]; xin[r] = xac[r]; }
      }
    }
  }

  // ---- outputs
  if (p0 + lr < n) {
    float4 xa = {xac[0], xac[1], xac[2], xac[3]};
    *(float4*)(out + (size_t)(p0 + lr) * 16 + lg * 4) = xa;
    if (lg == 0) {
      out[(size_t)n * 16 + p0 + lr] = lacc;
      out[(size_t)n * 17 + p0 + lr] = vacc;
      out[(size_t)n * 18 + p0 + lr] = racc;
    }
  }
}

extern "C" void kernel_launch(void* const* d_in, const int* in_sizes, int n_in,
                              void* d_out, int out_size, void* d_ws, size_t ws_size,
                              hipStream_t stream) {
  const float* xg = (const float*)d_in[0];
  const float* wg = (const float*)d_in[1];
  const float* Ag = (const float*)d_in[2];
  const float* bg = (const float*)d_in[3];
  const float* K0g = (const float*)d_in[4];
  const float* b0g = (const float*)d_in[5];
  const float* K1g = (const float*)d_in[6];
  const float* b1g = (const float*)d_in[7];
  const int* ntg = (const int*)d_in[8];
  float* out = (float*)d_out;
  float* ws = (float*)d_ws;
  int n = in_sizes[0] / 16;

  hipLaunchKernelGGL(otflow_prep, dim3(1), dim3(256), 0, stream, K0g, Ag, ws);
  int nblk = (n + 15) / 16;
  hipLaunchKernelGGL(otflow_main, dim3(nblk), dim3(64), 0, stream,
                     xg, wg, bg, K0g, b0g, K1g, b1g, ntg, ws, out, n);
}